// Round 1
// baseline (120.748 us; speedup 1.0000x reference)
//
#include <hip/hip_runtime.h>

// Problem constants (from reference setup_inputs):
//   B=4, N=8192, C=256, NEIGHBOR_NUM=4, POOLING_RATE=4 -> P = N/4 = 2048
// Outputs (concatenated flat in d_out):
//   vertices_pool    (B, P, 3)   float32
//   feature_map_pool (B, P, C)   float32
//
// Reference semantics: for each point n, neighbors = the 4 SMALLEST indices m
// with dist2(n,m) <= radius^2 (self forced in via zeroed diagonal), padded
// with the first hit if fewer than 4. Max-pool features over those 4, then
// gather rows sample_idx. We only compute at the 2048 sampled indices.

#define BB 4
#define NN 8192
#define CC 256
#define PP 2048
#define KK 4

__global__ __launch_bounds__(256) void pool_layer_kernel(
    const float* __restrict__ vertices,   // (B, N, 3)
    const float* __restrict__ feat,       // (B, N, C)
    const int*   __restrict__ radius_p,   // (1,)
    const int*   __restrict__ sample_idx, // (P,)
    float* __restrict__ out_v,            // (B, P, 3)
    float* __restrict__ out_f)            // (B, P, C)
{
    const int wave = threadIdx.x >> 6;
    const int lane = threadIdx.x & 63;
    const int q    = blockIdx.x * 4 + wave;    // query id in [0, B*P)
    const int b    = q >> 11;                  // q / P   (P = 2048)
    const int i    = q & (PP - 1);             // q % P
    const int n    = sample_idx[i];

    const float* vb = vertices + (size_t)b * NN * 3;

    // Query point + its squared norm, in the reference's exact fp32 order:
    // sq = ((x*x) + (y*y)) + (z*z); no FMA contraction (use _rn intrinsics).
    const float xn0 = vb[n * 3 + 0];
    const float xn1 = vb[n * 3 + 1];
    const float xn2 = vb[n * 3 + 2];
    const float sqn = __fadd_rn(__fadd_rn(__fmul_rn(xn0, xn0),
                                          __fmul_rn(xn1, xn1)),
                                __fmul_rn(xn2, xn2));

    const int   r  = radius_p[0];
    const float r2 = (float)(r * r);

    // vertices_pool gather (lanes 0..2 write x,y,z)
    if (lane < 3) {
        out_v[((size_t)b * PP + i) * 3 + lane] = vb[n * 3 + lane];
    }

    // Scan indices in ascending order, 64 at a time; collect first 4 hits.
    int cand[KK];
    int cnt = 0;
    for (int base = 0; base < NN && cnt < KK; base += 64) {
        const int m = base + lane;
        const float x0 = vb[m * 3 + 0];
        const float x1 = vb[m * 3 + 1];
        const float x2 = vb[m * 3 + 2];
        const float sqm = __fadd_rn(__fadd_rn(__fmul_rn(x0, x0),
                                              __fmul_rn(x1, x1)),
                                    __fmul_rn(x2, x2));
        const float dot = __fadd_rn(__fadd_rn(__fmul_rn(xn0, x0),
                                              __fmul_rn(xn1, x1)),
                                    __fmul_rn(xn2, x2));
        // dist = (-2*dot) + sq_n + sq_m, left-to-right, fp32, no fma
        const float dist = __fadd_rn(__fadd_rn(__fmul_rn(-2.0f, dot), sqn), sqm);
        // hit iff NOT (dist > r2); diagonal forced to 0 by the reference
        const bool hit = (m == n) || !(dist > r2);
        unsigned long long mask = __ballot(hit);
        // ballot result is wave-uniform -> every lane runs the same scalar
        // loop and ends with identical cand[]/cnt. No broadcast needed.
        while (mask && cnt < KK) {
            const int l = __ffsll(mask) - 1;
            cand[cnt++] = base + l;
            mask &= (mask - 1);
        }
    }
    // cnt >= 1 always (self-hit). Pad with first hit per reference.
    for (int j = cnt; j < KK; ++j) cand[j] = cand[0];

    // Max-pool 4 feature rows of 256 floats: 64 lanes x float4 = 1 row/load.
    const float4* f0 = (const float4*)(feat + ((size_t)b * NN + cand[0]) * CC);
    const float4* f1 = (const float4*)(feat + ((size_t)b * NN + cand[1]) * CC);
    const float4* f2 = (const float4*)(feat + ((size_t)b * NN + cand[2]) * CC);
    const float4* f3 = (const float4*)(feat + ((size_t)b * NN + cand[3]) * CC);
    const float4 a0 = f0[lane];
    const float4 a1 = f1[lane];
    const float4 a2 = f2[lane];
    const float4 a3 = f3[lane];
    float4 o;
    o.x = fmaxf(fmaxf(a0.x, a1.x), fmaxf(a2.x, a3.x));
    o.y = fmaxf(fmaxf(a0.y, a1.y), fmaxf(a2.y, a3.y));
    o.z = fmaxf(fmaxf(a0.z, a1.z), fmaxf(a2.z, a3.z));
    o.w = fmaxf(fmaxf(a0.w, a1.w), fmaxf(a2.w, a3.w));
    ((float4*)(out_f + ((size_t)b * PP + i) * CC))[lane] = o;
}

extern "C" void kernel_launch(void* const* d_in, const int* in_sizes, int n_in,
                              void* d_out, int out_size, void* d_ws, size_t ws_size,
                              hipStream_t stream) {
    const float* vertices   = (const float*)d_in[0]; // (B,N,3) fp32
    const float* feat       = (const float*)d_in[1]; // (B,N,C) fp32
    const int*   radius_p   = (const int*)d_in[2];   // scalar int
    const int*   sample_idx = (const int*)d_in[3];   // (P,) int32

    float* out_v = (float*)d_out;                    // (B,P,3)
    float* out_f = out_v + (size_t)BB * PP * 3;      // (B,P,C)

    const int queries = BB * PP;                     // 8192 waves
    dim3 grid(queries / 4), block(256);              // 4 waves/block
    pool_layer_kernel<<<grid, block, 0, stream>>>(
        vertices, feat, radius_p, sample_idx, out_v, out_f);
}

// Round 2
// 95.306 us; speedup vs baseline: 1.2670x; 1.2670x over previous
//
#include <hip/hip_runtime.h>

// Problem constants (from reference setup_inputs):
//   B=4, N=8192, C=256, NEIGHBOR_NUM=4, POOLING_RATE=4 -> P = N/4 = 2048
// Outputs (concatenated flat in d_out):
//   vertices_pool    (B, P, 3)   float32
//   feature_map_pool (B, P, C)   float32
//
// Reference semantics: for each point n, neighbors = the 4 SMALLEST indices m
// with dist2(n,m) <= radius^2 (self forced in via zeroed diagonal), padded
// with the first hit if fewer than 4. We only compute at the sampled indices.
//
// R1 -> R2: the 47.5us was a latency-bound straggler tail (VALUBusy 2.8%,
// HBM 3.4%): worst-case queries scan all 128 chunks of 64 candidates with a
// serial load->ballot->branch dependency per chunk. Fix: batch 8 chunks (512
// candidates) per early-exit iteration so the 24 per-lane loads pipeline and
// the serial chain is 16 iterations max instead of 128.

#define BB 4
#define NN 8192
#define CC 256
#define PP 2048
#define KK 4
#define CH 8   // chunks of 64 candidates in flight per early-exit iteration

__global__ __launch_bounds__(256) void pool_layer_kernel(
    const float* __restrict__ vertices,   // (B, N, 3)
    const float* __restrict__ feat,       // (B, N, C)
    const int*   __restrict__ radius_p,   // (1,)
    const int*   __restrict__ sample_idx, // (P,)
    float* __restrict__ out_v,            // (B, P, 3)
    float* __restrict__ out_f)            // (B, P, C)
{
    const int wave = threadIdx.x >> 6;
    const int lane = threadIdx.x & 63;
    const int q    = blockIdx.x * 4 + wave;    // query id in [0, B*P)
    const int b    = q >> 11;                  // q / P   (P = 2048)
    const int i    = q & (PP - 1);             // q % P
    const int n    = sample_idx[i];

    const float* vb = vertices + (size_t)b * NN * 3;

    // Query point + its squared norm, in the reference's exact fp32 order:
    // sq = ((x*x) + (y*y)) + (z*z); no FMA contraction (use _rn intrinsics).
    const float xn0 = vb[n * 3 + 0];
    const float xn1 = vb[n * 3 + 1];
    const float xn2 = vb[n * 3 + 2];
    const float sqn = __fadd_rn(__fadd_rn(__fmul_rn(xn0, xn0),
                                          __fmul_rn(xn1, xn1)),
                                __fmul_rn(xn2, xn2));

    const int   r  = radius_p[0];
    const float r2 = (float)(r * r);

    // vertices_pool gather (lanes 0..2 write x,y,z)
    if (lane < 3) {
        out_v[((size_t)b * PP + i) * 3 + lane] = vb[n * 3 + lane];
    }

    // Scan indices in ascending order, CH*64 at a time; collect first 4 hits.
    int cand[KK];
    int cnt = 0;
    for (int base = 0; base < NN && cnt < KK; base += 64 * CH) {
        unsigned long long masks[CH];
        #pragma unroll
        for (int c = 0; c < CH; ++c) {
            const int m = base + 64 * c + lane;
            const float x0 = vb[m * 3 + 0];
            const float x1 = vb[m * 3 + 1];
            const float x2 = vb[m * 3 + 2];
            const float sqm = __fadd_rn(__fadd_rn(__fmul_rn(x0, x0),
                                                  __fmul_rn(x1, x1)),
                                        __fmul_rn(x2, x2));
            const float dot = __fadd_rn(__fadd_rn(__fmul_rn(xn0, x0),
                                                  __fmul_rn(xn1, x1)),
                                        __fmul_rn(xn2, x2));
            // dist = (-2*dot) + sq_n + sq_m, left-to-right, fp32, no fma
            const float dist = __fadd_rn(__fadd_rn(__fmul_rn(-2.0f, dot), sqn), sqm);
            // hit iff NOT (dist > r2); diagonal forced to 0 by the reference
            masks[c] = __ballot((m == n) || !(dist > r2));
        }
        #pragma unroll
        for (int c = 0; c < CH; ++c) {
            // masks are wave-uniform -> every lane runs the same scalar loop
            unsigned long long mask = masks[c];
            while (mask && cnt < KK) {
                const int l = __ffsll(mask) - 1;
                cand[cnt++] = base + 64 * c + l;
                mask &= (mask - 1);
            }
        }
    }
    // cnt >= 1 always (self-hit). Pad with first hit per reference.
    for (int j = cnt; j < KK; ++j) cand[j] = cand[0];

    // Max-pool 4 feature rows of 256 floats: 64 lanes x float4 = 1 row/load.
    const float4* f0 = (const float4*)(feat + ((size_t)b * NN + cand[0]) * CC);
    const float4* f1 = (const float4*)(feat + ((size_t)b * NN + cand[1]) * CC);
    const float4* f2 = (const float4*)(feat + ((size_t)b * NN + cand[2]) * CC);
    const float4* f3 = (const float4*)(feat + ((size_t)b * NN + cand[3]) * CC);
    const float4 a0 = f0[lane];
    const float4 a1 = f1[lane];
    const float4 a2 = f2[lane];
    const float4 a3 = f3[lane];
    float4 o;
    o.x = fmaxf(fmaxf(a0.x, a1.x), fmaxf(a2.x, a3.x));
    o.y = fmaxf(fmaxf(a0.y, a1.y), fmaxf(a2.y, a3.y));
    o.z = fmaxf(fmaxf(a0.z, a1.z), fmaxf(a2.z, a3.z));
    o.w = fmaxf(fmaxf(a0.w, a1.w), fmaxf(a2.w, a3.w));
    ((float4*)(out_f + ((size_t)b * PP + i) * CC))[lane] = o;
}

extern "C" void kernel_launch(void* const* d_in, const int* in_sizes, int n_in,
                              void* d_out, int out_size, void* d_ws, size_t ws_size,
                              hipStream_t stream) {
    const float* vertices   = (const float*)d_in[0]; // (B,N,3) fp32
    const float* feat       = (const float*)d_in[1]; // (B,N,C) fp32
    const int*   radius_p   = (const int*)d_in[2];   // scalar int
    const int*   sample_idx = (const int*)d_in[3];   // (P,) int32

    float* out_v = (float*)d_out;                    // (B,P,3)
    float* out_f = out_v + (size_t)BB * PP * 3;      // (B,P,C)

    const int queries = BB * PP;                     // 8192 waves
    dim3 grid(queries / 4), block(256);              // 4 waves/block
    pool_layer_kernel<<<grid, block, 0, stream>>>(
        vertices, feat, radius_p, sample_idx, out_v, out_f);
}